// Round 14
// baseline (553.476 us; speedup 1.0000x reference)
//
#include <hip/hip_runtime.h>

// PointConv fused kernel for MI355X (gfx950).
// B=1, N=200000, K=16, C_IN=3, C_MID=16, HIDDEN=[8,8], LAST_CH=6, C_OUT=64.
// R7:  311 us | VALUBusy 44% | WRITE 239 MB | FETCH 98 MB | VGPR 128.
// R8:  250 us | VALUBusy 55% | WRITE 177 MB | FETCH 149 MB | VGPR 128.
//      (nt-revert + lw->LDS; lw-LDS mechanism confirmed, -60us)
// R12 theory: VGPR_Count pinned at 128 while K-loop live set ~170 => compiler
//      spills ~40 regs; scratch store+reload ~= 435 B/thread matches BOTH the
//      87 MB WRITE excess and ~90 MB FETCH excess. Also the K-loop re-streams
//      280 weight floats/iter through the maxed SGPR file (s_load batches).
// R12: (1) __launch_bounds__(256,3) -> VGPR cap ~170, no spill, 12 waves/CU.
//      (2) WeightNet weights staged in LDS, transposed per-output rows
//          {wT[.], g, b} read as uniform-address ds_read_b128/b64 broadcasts.
//      (3) wni stored every 4 k in-loop; lxyz buffer 48 -> 12 floats.
// R13/R14: resubmissions of R12 unchanged (broker timeouts; R12 unmeasured).

constexpr int K     = 16;
constexpr int C_OUT = 64;
constexpr int ACC   = 96;   // LAST_CH(6) * C_MID(16)

typedef float f32x4 __attribute__((ext_vector_type(4)));
typedef float f32x2 __attribute__((ext_vector_type(2)));

__global__ __launch_bounds__(256, 3) void pointconv_fused(
    const float* __restrict__ xyz,    // [N,3]
    const float* __restrict__ feats,  // [N,3]
    const int*   __restrict__ nei,    // [N,K]
    const float* __restrict__ w1, const float* __restrict__ g1, const float* __restrict__ b1,
    const float* __restrict__ w2, const float* __restrict__ g2, const float* __restrict__ b2,
    const float* __restrict__ w3, const float* __restrict__ g3, const float* __restrict__ b3,
    const float* __restrict__ lw,     // [96,64]
    const float* __restrict__ lb,     // [64]
    float* __restrict__ out_feat,     // [N,64]
    float* __restrict__ out_wni,      // [N,K,3]
    int n_pts)
{
    __shared__ float slw[ACC * C_OUT];   // 24 KB  final-linear weights [j][o]
    __shared__ float slb[C_OUT];
    // WeightNet weights, transposed to per-output rows (uniform ds_read rows):
    __shared__ float sL1[8 * 8];    // row o (stride 8):  w1T[0..2], g1, b1, pad3
    __shared__ float sL2[8 * 16];   // row o (stride 16): w2T[0..7], g2, b2, pad6
    __shared__ float sL3[16 * 12];  // row o (stride 12): w3T[0..7], g3, b3, pad2

    const int tid = threadIdx.x;

    // ---- cooperative staging (all 256 threads alive; before any early-out) ----
    {
        const f32x4* src = reinterpret_cast<const f32x4*>(lw);
        f32x4*       dst = reinterpret_cast<f32x4*>(slw);
#pragma unroll
        for (int i = 0; i < 6; ++i)                 // 1536 f32x4 / 256 threads
            dst[tid + i * 256] = src[tid + i * 256];
        if (tid < C_OUT / 4)
            reinterpret_cast<f32x4*>(slb)[tid] =
                reinterpret_cast<const f32x4*>(lb)[tid];
    }
    if (tid < 8) {
        sL1[tid * 8 + 0] = w1[0 * 8 + tid];
        sL1[tid * 8 + 1] = w1[1 * 8 + tid];
        sL1[tid * 8 + 2] = w1[2 * 8 + tid];
        sL1[tid * 8 + 3] = g1[tid];
        sL1[tid * 8 + 4] = b1[tid];
#pragma unroll
        for (int i = 0; i < 8; ++i) sL2[tid * 16 + i] = w2[i * 8 + tid];
        sL2[tid * 16 + 8] = g2[tid];
        sL2[tid * 16 + 9] = b2[tid];
    }
    if (tid < 16) {
#pragma unroll
        for (int i = 0; i < 8; ++i) sL3[tid * 12 + i] = w3[i * 16 + tid];
        sL3[tid * 12 + 8] = g3[tid];
        sL3[tid * 12 + 9] = b3[tid];
    }
    __syncthreads();

    const int n = blockIdx.x * blockDim.x + tid;
    if (n >= n_pts) return;

    const float cx = xyz[n * 3 + 0];
    const float cy = xyz[n * 3 + 1];
    const float cz = xyz[n * 3 + 2];

    int idx[K];
    {
        const int4* p = reinterpret_cast<const int4*>(nei + (size_t)n * K);
        int4 a = p[0], b = p[1], c = p[2], d = p[3];
        idx[0] = a.x; idx[1] = a.y; idx[2]  = a.z; idx[3]  = a.w;
        idx[4] = b.x; idx[5] = b.y; idx[6]  = b.z; idx[7]  = b.w;
        idx[8] = c.x; idx[9] = c.y; idx[10] = c.z; idx[11] = c.w;
        idx[12] = d.x; idx[13] = d.y; idx[14] = d.z; idx[15] = d.w;
    }

    float acc[ACC];
#pragma unroll
    for (int i = 0; i < ACC; ++i) acc[i] = 0.f;

    float lxyz[12];                  // 4 neighbors' relative coords (was 48)

#pragma unroll
    for (int k = 0; k < K; ++k) {
        const int j = idx[k];
        const float nx = xyz[(size_t)j * 3 + 0];
        const float ny = xyz[(size_t)j * 3 + 1];
        const float nz = xyz[(size_t)j * 3 + 2];
        const float f0 = feats[(size_t)j * 3 + 0];
        const float f1 = feats[(size_t)j * 3 + 1];
        const float f2 = feats[(size_t)j * 3 + 2];

        const float lx = nx - cx;
        const float ly = ny - cy;
        const float lz = nz - cz;

        lxyz[(k & 3) * 3 + 0] = lx;
        lxyz[(k & 3) * 3 + 1] = ly;
        lxyz[(k & 3) * 3 + 2] = lz;

        // WeightNet layer 1: 3 -> 8  (row: w0,w1,w2,g | b)
        float h1[8];
#pragma unroll
        for (int o = 0; o < 8; ++o) {
            f32x4 r = *reinterpret_cast<const f32x4*>(&sL1[o * 8]);
            float bb = sL1[o * 8 + 4];
            float s = lx * r.x + ly * r.y + lz * r.z;
            h1[o] = fmaxf(fmaf(s, r.w, bb), 0.f);
        }
        // layer 2: 8 -> 8
        float h2[8];
#pragma unroll
        for (int o = 0; o < 8; ++o) {
            f32x4 wa = *reinterpret_cast<const f32x4*>(&sL2[o * 16]);
            f32x4 wb = *reinterpret_cast<const f32x4*>(&sL2[o * 16 + 4]);
            f32x2 gb = *reinterpret_cast<const f32x2*>(&sL2[o * 16 + 8]);
            float s = h1[0] * wa.x;
            s = fmaf(h1[1], wa.y, s); s = fmaf(h1[2], wa.z, s);
            s = fmaf(h1[3], wa.w, s); s = fmaf(h1[4], wb.x, s);
            s = fmaf(h1[5], wb.y, s); s = fmaf(h1[6], wb.z, s);
            s = fmaf(h1[7], wb.w, s);
            h2[o] = fmaxf(fmaf(s, gb.x, gb.y), 0.f);
        }
        // layer 3: 8 -> 16
        float h3[16];
#pragma unroll
        for (int o = 0; o < 16; ++o) {
            f32x4 wa = *reinterpret_cast<const f32x4*>(&sL3[o * 12]);
            f32x4 wb = *reinterpret_cast<const f32x4*>(&sL3[o * 12 + 4]);
            f32x2 gb = *reinterpret_cast<const f32x2*>(&sL3[o * 12 + 8]);
            float s = h2[0] * wa.x;
            s = fmaf(h2[1], wa.y, s); s = fmaf(h2[2], wa.z, s);
            s = fmaf(h2[3], wa.w, s); s = fmaf(h2[4], wb.x, s);
            s = fmaf(h2[5], wb.y, s); s = fmaf(h2[6], wb.z, s);
            s = fmaf(h2[7], wb.w, s);
            h3[o] = fmaxf(fmaf(s, gb.x, gb.y), 0.f);
        }

        // acc[c][w] += cval[c] * h3[w]; channels: feats(3) then rel-coords(3)
        const float c0 = f0, c1 = f1, c2 = f2, c3 = lx, c4 = ly, c5 = lz;
#pragma unroll
        for (int w = 0; w < 16; ++w) {
            const float h = h3[w];
            acc[0 * 16 + w] = fmaf(c0, h, acc[0 * 16 + w]);
            acc[1 * 16 + w] = fmaf(c1, h, acc[1 * 16 + w]);
            acc[2 * 16 + w] = fmaf(c2, h, acc[2 * 16 + w]);
            acc[3 * 16 + w] = fmaf(c3, h, acc[3 * 16 + w]);
            acc[4 * 16 + w] = fmaf(c4, h, acc[4 * 16 + w]);
            acc[5 * 16 + w] = fmaf(c5, h, acc[5 * 16 + w]);
        }

        // flush 4 neighbors' weightNetInput (3x 16B, offsets 0/48/96/144 B)
        if ((k & 3) == 3) {
            f32x4* wp = reinterpret_cast<f32x4*>(
                out_wni + (size_t)n * (K * 3) + (k - 3) * 3);
            f32x4 v0 = { lxyz[0], lxyz[1], lxyz[2],  lxyz[3] };
            f32x4 v1 = { lxyz[4], lxyz[5], lxyz[6],  lxyz[7] };
            f32x4 v2 = { lxyz[8], lxyz[9], lxyz[10], lxyz[11] };
            wp[0] = v0; wp[1] = v1; wp[2] = v2;
        }
    }

    // Final linear from LDS (uniform-address broadcasts), chunked o-groups of 16.
#pragma unroll 1
    for (int ch = 0; ch < 4; ++ch) {
        const int o0 = ch * 16;
        float o16[16];
#pragma unroll
        for (int t = 0; t < 16; ++t) o16[t] = slb[o0 + t];
#pragma unroll
        for (int j2 = 0; j2 < ACC; ++j2) {
            const float a = acc[j2];
#pragma unroll
            for (int t = 0; t < 16; ++t)
                o16[t] = fmaf(a, slw[j2 * C_OUT + o0 + t], o16[t]);
        }
        f32x4* op = reinterpret_cast<f32x4*>(out_feat + (size_t)n * 64 + o0);
#pragma unroll
        for (int t = 0; t < 4; ++t) {
            f32x4 v = { fmaxf(o16[4 * t + 0], 0.f),
                        fmaxf(o16[4 * t + 1], 0.f),
                        fmaxf(o16[4 * t + 2], 0.f),
                        fmaxf(o16[4 * t + 3], 0.f) };
            op[t] = v;
        }
    }
}

extern "C" void kernel_launch(void* const* d_in, const int* in_sizes, int n_in,
                              void* d_out, int out_size, void* d_ws, size_t ws_size,
                              hipStream_t stream) {
    const float* xyz   = (const float*)d_in[0];
    const float* feats = (const float*)d_in[1];
    const int*   nei   = (const int*)d_in[2];
    const float* w1 = (const float*)d_in[3];
    const float* g1 = (const float*)d_in[4];
    const float* b1 = (const float*)d_in[5];
    const float* w2 = (const float*)d_in[6];
    const float* g2 = (const float*)d_in[7];
    const float* b2 = (const float*)d_in[8];
    const float* w3 = (const float*)d_in[9];
    const float* g3 = (const float*)d_in[10];
    const float* b3 = (const float*)d_in[11];
    const float* lw = (const float*)d_in[12];
    const float* lb = (const float*)d_in[13];

    const int n_pts = in_sizes[0] / 3;              // xyz is [N,3]

    float* out = (float*)d_out;
    float* out_feat = out;                          // [N,64] first in return order
    float* out_wni  = out + (size_t)n_pts * C_OUT;  // then [N,K,3]

    const int threads = 256;
    const int blocks  = (n_pts + threads - 1) / threads;
    pointconv_fused<<<blocks, threads, 0, stream>>>(
        xyz, feats, nei,
        w1, g1, b1, w2, g2, b2, w3, g3, b3,
        lw, lb, out_feat, out_wni, n_pts);
}

// Round 15
// 283.582 us; speedup vs baseline: 1.9517x; 1.9517x over previous
//
#include <hip/hip_runtime.h>

// PointConv fused kernel for MI355X (gfx950).
// B=1, N=200000, K=16, C_IN=3, C_MID=16, HIDDEN=[8,8], LAST_CH=6, C_OUT=64.
// R7:  311 us | VALUBusy 44% | WRITE 239 | FETCH  98 | VGPR 128 | lb(256,2)
// R8:  250 us | VALUBusy 55% | WRITE 177 | FETCH 149 | VGPR 128 | lb(256,2)
// R12: 450 us | VALUBusy 14% | WRITE 496 | FETCH 410 | VGPR  84 | lb(256,3)
// R12 lesson: hipcc maps __launch_bounds__ arg2=N to a ~2N-waves/SIMD VGPR cap
//   (2->128, 3->84 = 512/6). (256,3) CUT the cap instead of raising it ->
//   ~90 spilled regs -> ~2 KB/thread scratch -> scratch-BW-bound (2.1 TB/s
//   through TCC), VALUBusy collapsed. Occupancy ROSE to 25.7% while perf
//   halved: occupancy is not the constraint, spill traffic is.
// R15: SINGLE change vs R12 -> __launch_bounds__(256,1): cap 512/2 = 256 VGPR,
//   live set ~170 fits, zero spill. Predict VGPR 160-220, WRITE ~95 MB,
//   FETCH 55-85 MB, VALUBusy 55-75%, dur 120-180 us.

constexpr int K     = 16;
constexpr int C_OUT = 64;
constexpr int ACC   = 96;   // LAST_CH(6) * C_MID(16)

typedef float f32x4 __attribute__((ext_vector_type(4)));
typedef float f32x2 __attribute__((ext_vector_type(2)));

__global__ __launch_bounds__(256, 1) void pointconv_fused(
    const float* __restrict__ xyz,    // [N,3]
    const float* __restrict__ feats,  // [N,3]
    const int*   __restrict__ nei,    // [N,K]
    const float* __restrict__ w1, const float* __restrict__ g1, const float* __restrict__ b1,
    const float* __restrict__ w2, const float* __restrict__ g2, const float* __restrict__ b2,
    const float* __restrict__ w3, const float* __restrict__ g3, const float* __restrict__ b3,
    const float* __restrict__ lw,     // [96,64]
    const float* __restrict__ lb,     // [64]
    float* __restrict__ out_feat,     // [N,64]
    float* __restrict__ out_wni,      // [N,K,3]
    int n_pts)
{
    __shared__ float slw[ACC * C_OUT];   // 24 KB  final-linear weights [j][o]
    __shared__ float slb[C_OUT];
    // WeightNet weights, transposed to per-output rows (uniform ds_read rows):
    __shared__ float sL1[8 * 8];    // row o (stride 8):  w1T[0..2], g1, b1, pad3
    __shared__ float sL2[8 * 16];   // row o (stride 16): w2T[0..7], g2, b2, pad6
    __shared__ float sL3[16 * 12];  // row o (stride 12): w3T[0..7], g3, b3, pad2

    const int tid = threadIdx.x;

    // ---- cooperative staging (all 256 threads alive; before any early-out) ----
    {
        const f32x4* src = reinterpret_cast<const f32x4*>(lw);
        f32x4*       dst = reinterpret_cast<f32x4*>(slw);
#pragma unroll
        for (int i = 0; i < 6; ++i)                 // 1536 f32x4 / 256 threads
            dst[tid + i * 256] = src[tid + i * 256];
        if (tid < C_OUT / 4)
            reinterpret_cast<f32x4*>(slb)[tid] =
                reinterpret_cast<const f32x4*>(lb)[tid];
    }
    if (tid < 8) {
        sL1[tid * 8 + 0] = w1[0 * 8 + tid];
        sL1[tid * 8 + 1] = w1[1 * 8 + tid];
        sL1[tid * 8 + 2] = w1[2 * 8 + tid];
        sL1[tid * 8 + 3] = g1[tid];
        sL1[tid * 8 + 4] = b1[tid];
#pragma unroll
        for (int i = 0; i < 8; ++i) sL2[tid * 16 + i] = w2[i * 8 + tid];
        sL2[tid * 16 + 8] = g2[tid];
        sL2[tid * 16 + 9] = b2[tid];
    }
    if (tid < 16) {
#pragma unroll
        for (int i = 0; i < 8; ++i) sL3[tid * 12 + i] = w3[i * 16 + tid];
        sL3[tid * 12 + 8] = g3[tid];
        sL3[tid * 12 + 9] = b3[tid];
    }
    __syncthreads();

    const int n = blockIdx.x * blockDim.x + tid;
    if (n >= n_pts) return;

    const float cx = xyz[n * 3 + 0];
    const float cy = xyz[n * 3 + 1];
    const float cz = xyz[n * 3 + 2];

    int idx[K];
    {
        const int4* p = reinterpret_cast<const int4*>(nei + (size_t)n * K);
        int4 a = p[0], b = p[1], c = p[2], d = p[3];
        idx[0] = a.x; idx[1] = a.y; idx[2]  = a.z; idx[3]  = a.w;
        idx[4] = b.x; idx[5] = b.y; idx[6]  = b.z; idx[7]  = b.w;
        idx[8] = c.x; idx[9] = c.y; idx[10] = c.z; idx[11] = c.w;
        idx[12] = d.x; idx[13] = d.y; idx[14] = d.z; idx[15] = d.w;
    }

    float acc[ACC];
#pragma unroll
    for (int i = 0; i < ACC; ++i) acc[i] = 0.f;

    float lxyz[12];                  // 4 neighbors' relative coords

#pragma unroll
    for (int k = 0; k < K; ++k) {
        const int j = idx[k];
        const float nx = xyz[(size_t)j * 3 + 0];
        const float ny = xyz[(size_t)j * 3 + 1];
        const float nz = xyz[(size_t)j * 3 + 2];
        const float f0 = feats[(size_t)j * 3 + 0];
        const float f1 = feats[(size_t)j * 3 + 1];
        const float f2 = feats[(size_t)j * 3 + 2];

        const float lx = nx - cx;
        const float ly = ny - cy;
        const float lz = nz - cz;

        lxyz[(k & 3) * 3 + 0] = lx;
        lxyz[(k & 3) * 3 + 1] = ly;
        lxyz[(k & 3) * 3 + 2] = lz;

        // WeightNet layer 1: 3 -> 8  (row: w0,w1,w2,g | b)
        float h1[8];
#pragma unroll
        for (int o = 0; o < 8; ++o) {
            f32x4 r = *reinterpret_cast<const f32x4*>(&sL1[o * 8]);
            float bb = sL1[o * 8 + 4];
            float s = lx * r.x + ly * r.y + lz * r.z;
            h1[o] = fmaxf(fmaf(s, r.w, bb), 0.f);
        }
        // layer 2: 8 -> 8
        float h2[8];
#pragma unroll
        for (int o = 0; o < 8; ++o) {
            f32x4 wa = *reinterpret_cast<const f32x4*>(&sL2[o * 16]);
            f32x4 wb = *reinterpret_cast<const f32x4*>(&sL2[o * 16 + 4]);
            f32x2 gb = *reinterpret_cast<const f32x2*>(&sL2[o * 16 + 8]);
            float s = h1[0] * wa.x;
            s = fmaf(h1[1], wa.y, s); s = fmaf(h1[2], wa.z, s);
            s = fmaf(h1[3], wa.w, s); s = fmaf(h1[4], wb.x, s);
            s = fmaf(h1[5], wb.y, s); s = fmaf(h1[6], wb.z, s);
            s = fmaf(h1[7], wb.w, s);
            h2[o] = fmaxf(fmaf(s, gb.x, gb.y), 0.f);
        }
        // layer 3: 8 -> 16
        float h3[16];
#pragma unroll
        for (int o = 0; o < 16; ++o) {
            f32x4 wa = *reinterpret_cast<const f32x4*>(&sL3[o * 12]);
            f32x4 wb = *reinterpret_cast<const f32x4*>(&sL3[o * 12 + 4]);
            f32x2 gb = *reinterpret_cast<const f32x2*>(&sL3[o * 12 + 8]);
            float s = h2[0] * wa.x;
            s = fmaf(h2[1], wa.y, s); s = fmaf(h2[2], wa.z, s);
            s = fmaf(h2[3], wa.w, s); s = fmaf(h2[4], wb.x, s);
            s = fmaf(h2[5], wb.y, s); s = fmaf(h2[6], wb.z, s);
            s = fmaf(h2[7], wb.w, s);
            h3[o] = fmaxf(fmaf(s, gb.x, gb.y), 0.f);
        }

        // acc[c][w] += cval[c] * h3[w]; channels: feats(3) then rel-coords(3)
        const float c0 = f0, c1 = f1, c2 = f2, c3 = lx, c4 = ly, c5 = lz;
#pragma unroll
        for (int w = 0; w < 16; ++w) {
            const float h = h3[w];
            acc[0 * 16 + w] = fmaf(c0, h, acc[0 * 16 + w]);
            acc[1 * 16 + w] = fmaf(c1, h, acc[1 * 16 + w]);
            acc[2 * 16 + w] = fmaf(c2, h, acc[2 * 16 + w]);
            acc[3 * 16 + w] = fmaf(c3, h, acc[3 * 16 + w]);
            acc[4 * 16 + w] = fmaf(c4, h, acc[4 * 16 + w]);
            acc[5 * 16 + w] = fmaf(c5, h, acc[5 * 16 + w]);
        }

        // flush 4 neighbors' weightNetInput (3x 16B, offsets 0/48/96/144 B)
        if ((k & 3) == 3) {
            f32x4* wp = reinterpret_cast<f32x4*>(
                out_wni + (size_t)n * (K * 3) + (k - 3) * 3);
            f32x4 v0 = { lxyz[0], lxyz[1], lxyz[2],  lxyz[3] };
            f32x4 v1 = { lxyz[4], lxyz[5], lxyz[6],  lxyz[7] };
            f32x4 v2 = { lxyz[8], lxyz[9], lxyz[10], lxyz[11] };
            wp[0] = v0; wp[1] = v1; wp[2] = v2;
        }
    }

    // Final linear from LDS (uniform-address broadcasts), chunked o-groups of 16.
#pragma unroll 1
    for (int ch = 0; ch < 4; ++ch) {
        const int o0 = ch * 16;
        float o16[16];
#pragma unroll
        for (int t = 0; t < 16; ++t) o16[t] = slb[o0 + t];
#pragma unroll
        for (int j2 = 0; j2 < ACC; ++j2) {
            const float a = acc[j2];
#pragma unroll
            for (int t = 0; t < 16; ++t)
                o16[t] = fmaf(a, slw[j2 * C_OUT + o0 + t], o16[t]);
        }
        f32x4* op = reinterpret_cast<f32x4*>(out_feat + (size_t)n * 64 + o0);
#pragma unroll
        for (int t = 0; t < 4; ++t) {
            f32x4 v = { fmaxf(o16[4 * t + 0], 0.f),
                        fmaxf(o16[4 * t + 1], 0.f),
                        fmaxf(o16[4 * t + 2], 0.f),
                        fmaxf(o16[4 * t + 3], 0.f) };
            op[t] = v;
        }
    }
}

extern "C" void kernel_launch(void* const* d_in, const int* in_sizes, int n_in,
                              void* d_out, int out_size, void* d_ws, size_t ws_size,
                              hipStream_t stream) {
    const float* xyz   = (const float*)d_in[0];
    const float* feats = (const float*)d_in[1];
    const int*   nei   = (const int*)d_in[2];
    const float* w1 = (const float*)d_in[3];
    const float* g1 = (const float*)d_in[4];
    const float* b1 = (const float*)d_in[5];
    const float* w2 = (const float*)d_in[6];
    const float* g2 = (const float*)d_in[7];
    const float* b2 = (const float*)d_in[8];
    const float* w3 = (const float*)d_in[9];
    const float* g3 = (const float*)d_in[10];
    const float* b3 = (const float*)d_in[11];
    const float* lw = (const float*)d_in[12];
    const float* lb = (const float*)d_in[13];

    const int n_pts = in_sizes[0] / 3;              // xyz is [N,3]

    float* out = (float*)d_out;
    float* out_feat = out;                          // [N,64] first in return order
    float* out_wni  = out + (size_t)n_pts * C_OUT;  // then [N,K,3]

    const int threads = 256;
    const int blocks  = (n_pts + threads - 1) / threads;
    pointconv_fused<<<blocks, threads, 0, stream>>>(
        xyz, feats, nei,
        w1, g1, b1, w2, g2, b2, w3, g3, b3,
        lw, lb, out_feat, out_wni, n_pts);
}